// Round 15
// baseline (327.682 us; speedup 1.0000x reference)
//
#include <hip/hip_runtime.h>

#define N_NODES 51200
#define N_EDGES 819200
#define HDIM 128
#define AK 256          // GEMM K = 2*HDIM (agg | x)
#define NGRAPH 128
#define SEG 400
#define NOUT 10
#define SLOT 64         // contiguous col2 slot per node (deg ~ Poisson(16))
#define SSLOT 32        // per-(node,slice) sub-slot: 32 x 2B = one 64B line

typedef unsigned short ushort_t;
typedef unsigned int uint_t;
typedef __attribute__((ext_vector_type(8))) short bf16x8;
typedef __attribute__((ext_vector_type(16))) float f32x16;

static __device__ __forceinline__ unsigned short f2bf(float f) {
    unsigned int u = __float_as_uint(f);
    unsigned int r = (u + 0x7fffu + ((u >> 16) & 1u)) >> 16;  // RNE
    return (unsigned short)r;
}
static __device__ __forceinline__ float bf2f(unsigned short h) {
    return __uint_as_float(((unsigned int)h) << 16);
}

// ---------------- scatter (XCD-sliced): each 64B line written by ONE XCD ----------
// slice = blockIdx&7 (round-robin XCD heuristic, R4); col_s[(n*8+s)*32+pos]
// cnt8 slice-major so counter lines are single-XCD too

__global__ void k_scatter(const int* __restrict__ src, const int* __restrict__ dst,
                          int* __restrict__ cnt8, ushort_t* __restrict__ col_s) {
    int e = blockIdx.x * 256 + threadIdx.x;
    int s = blockIdx.x & 7;
    int d = dst[e];
    int pos = atomicAdd(&cnt8[s * N_NODES + d], 1);
    col_s[((size_t)d * 8 + s) * SSLOT + pos] = (ushort_t)src[e];
}

// ---------------- compact: 8 sub-slots -> contiguous col2[n*64..], cnt[n]=deg --------

__global__ void k_compact(const int* __restrict__ cnt8, const ushort_t* __restrict__ col_s,
                          ushort_t* __restrict__ col2, int* __restrict__ cnt) {
    int n = blockIdx.x * 256 + threadIdx.x;
    int total = 0;
    int base = n * SLOT;
    const ushort_t* p = col_s + (size_t)n * 8 * SSLOT;
#pragma unroll
    for (int s = 0; s < 8; ++s) {
        int c = cnt8[s * N_NODES + n];
        for (int e = 0; e < c; ++e) col2[base + total + e] = p[s * SSLOT + e];
        total += c;
    }
    cnt[n] = total;
}

// ---------------- prep: cast x0 -> Abuf right half, build Wfrags, zero pooled --------
// grid = 6400 (cast) + 128 (wfrag1) + 128 (wfrag2) + 64 (pooled zero) = 6720

__global__ void k_prep(const float* __restrict__ x, ushort_t* __restrict__ Abuf,
                       const float* __restrict__ W1rel, const float* __restrict__ W1root,
                       const float* __restrict__ W2rel, const float* __restrict__ W2root,
                       ushort_t* __restrict__ Wfrag1, ushort_t* __restrict__ Wfrag2,
                       float* __restrict__ pooled) {
    int b = blockIdx.x;
    if (b < 6400) {
        int idx = b * 256 + threadIdx.x;
        int row = idx >> 5;
        int c4 = (idx & 31) * 4;
        float4 v = *(const float4*)(x + (size_t)row * HDIM + c4);
        ushort4 h;
        h.x = f2bf(v.x); h.y = f2bf(v.y); h.z = f2bf(v.z); h.w = f2bf(v.w);
        *(ushort4*)(Abuf + (size_t)row * AK + HDIM + c4) = h;
    } else if (b < 6656) {
        int w2 = (b >= 6528);
        int tid = (b - (w2 ? 6528 : 6400)) * 256 + threadIdx.x;  // 0..32767
        const float* Wrel  = w2 ? W2rel : W1rel;
        const float* Wroot = w2 ? W2root : W1root;
        ushort_t* dstF     = w2 ? Wfrag2 : Wfrag1;
        int j = tid & 7;
        int l = (tid >> 3) & 63;
        int s = (tid >> 9) & 15;
        int t = tid >> 13;
        int k = 16 * s + (l >> 5) * 8 + j;
        int n = 32 * t + (l & 31);
        float v = (k < HDIM) ? Wrel[(size_t)k * HDIM + n]
                             : Wroot[(size_t)(k - HDIM) * HDIM + n];
        dstF[tid] = f2bf(v);
    } else {
        int i = (b - 6656) * 256 + threadIdx.x;  // 0..16383
        pooled[i] = 0.f;
    }
}

// ---------------- aggregation: quad-edge 16B gathers (R13) ----------------

__global__ __launch_bounds__(256) void k_aggregate(ushort_t* __restrict__ Abuf,
                                                   const int* __restrict__ cnt,
                                                   const ushort_t* __restrict__ col) {
    int wave = threadIdx.x >> 6;
    int lane = threadIdx.x & 63;
    int il = lane & 15;          // col group: cols 8*il..8*il+7 (16 B)
    int qe = lane >> 4;          // edge within quad: 0..3
    int node = blockIdx.x * 4 + wave;
    int beg = node * SLOT;
    int end = beg + cnt[node];

    const ushort_t* xsrc = Abuf + HDIM + (size_t)il * 8;

    float a[4][8];
#pragma unroll
    for (int j = 0; j < 4; ++j)
#pragma unroll
        for (int k = 0; k < 8; ++k) a[j][k] = 0.f;

    int e = beg;
    for (; e + 16 <= end; e += 16) {
        int c[4];
#pragma unroll
        for (int j = 0; j < 4; ++j) c[j] = (int)col[e + 4 * j + qe];
#pragma unroll
        for (int j = 0; j < 4; ++j) {
            uint4 v = *(const uint4*)(xsrc + (size_t)c[j] * AK);
            a[j][0] += __uint_as_float(v.x << 16);
            a[j][1] += __uint_as_float(v.x & 0xffff0000u);
            a[j][2] += __uint_as_float(v.y << 16);
            a[j][3] += __uint_as_float(v.y & 0xffff0000u);
            a[j][4] += __uint_as_float(v.z << 16);
            a[j][5] += __uint_as_float(v.z & 0xffff0000u);
            a[j][6] += __uint_as_float(v.w << 16);
            a[j][7] += __uint_as_float(v.w & 0xffff0000u);
        }
    }
    for (; e + 4 <= end; e += 4) {
        int c = (int)col[e + qe];
        uint4 v = *(const uint4*)(xsrc + (size_t)c * AK);
        a[0][0] += __uint_as_float(v.x << 16);
        a[0][1] += __uint_as_float(v.x & 0xffff0000u);
        a[0][2] += __uint_as_float(v.y << 16);
        a[0][3] += __uint_as_float(v.y & 0xffff0000u);
        a[0][4] += __uint_as_float(v.z << 16);
        a[0][5] += __uint_as_float(v.z & 0xffff0000u);
        a[0][6] += __uint_as_float(v.w << 16);
        a[0][7] += __uint_as_float(v.w & 0xffff0000u);
    }
    if (e < end) {
        int idx = e + qe;
        bool ok = idx < end;
        int c = (int)col[ok ? idx : e];
        uint4 v = *(const uint4*)(xsrc + (size_t)c * AK);
        a[1][0] += ok ? __uint_as_float(v.x << 16) : 0.f;
        a[1][1] += ok ? __uint_as_float(v.x & 0xffff0000u) : 0.f;
        a[1][2] += ok ? __uint_as_float(v.y << 16) : 0.f;
        a[1][3] += ok ? __uint_as_float(v.y & 0xffff0000u) : 0.f;
        a[1][4] += ok ? __uint_as_float(v.z << 16) : 0.f;
        a[1][5] += ok ? __uint_as_float(v.z & 0xffff0000u) : 0.f;
        a[1][6] += ok ? __uint_as_float(v.w << 16) : 0.f;
        a[1][7] += ok ? __uint_as_float(v.w & 0xffff0000u) : 0.f;
    }

    float s[8];
#pragma unroll
    for (int k = 0; k < 8; ++k) {
        s[k] = (a[0][k] + a[1][k]) + (a[2][k] + a[3][k]);
        s[k] += __shfl_xor(s[k], 16);
        s[k] += __shfl_xor(s[k], 32);
    }

    if (qe == 0) {
        uint4 o;
        o.x = (uint_t)f2bf(s[0]) | ((uint_t)f2bf(s[1]) << 16);
        o.y = (uint_t)f2bf(s[2]) | ((uint_t)f2bf(s[3]) << 16);
        o.z = (uint_t)f2bf(s[4]) | ((uint_t)f2bf(s[5]) << 16);
        o.w = (uint_t)f2bf(s[6]) | ((uint_t)f2bf(s[7]) << 16);
        *(uint4*)(Abuf + (size_t)node * AK + il * 8) = o;
    }
}

// ---------------- MFMA GEMM (layers 1-2): split-N, wave = 32 rows x 64 cols ---------

__global__ __launch_bounds__(64) void k_gemm_mfma(const ushort_t* __restrict__ Abuf,
                                                  const ushort_t* __restrict__ Wfrag,
                                                  const float* __restrict__ bias,
                                                  ushort_t* __restrict__ y) {
    __shared__ ushort_t sm[32][72];
    int lane = threadIdx.x;
    int nh = blockIdx.x & 1;
    int row0 = (blockIdx.x >> 1) * 32;
    int m = lane & 31;
    int half = lane >> 5;

    f32x16 acc[2];
#pragma unroll
    for (int t = 0; t < 2; ++t) acc[t] = (f32x16)(0.f);

    float bb[2];
#pragma unroll
    for (int t = 0; t < 2; ++t) bb[t] = bias[nh * 64 + t * 32 + m];

    const ushort_t* arow = Abuf + (size_t)(row0 + m) * AK + half * 8;
    const ushort_t* wf = Wfrag + (size_t)lane * 8 + (size_t)nh * 2 * 16 * 512;

#pragma unroll
    for (int s = 0; s < 16; ++s) {
        bf16x8 afrag = *(const bf16x8*)(arow + s * 16);
#pragma unroll
        for (int t = 0; t < 2; ++t) {
            bf16x8 bfrag = *(const bf16x8*)(wf + (size_t)(t * 16 + s) * 512);
            acc[t] = __builtin_amdgcn_mfma_f32_32x32x16_bf16(afrag, bfrag, acc[t], 0, 0, 0);
        }
    }

#pragma unroll
    for (int t = 0; t < 2; ++t) {
#pragma unroll
        for (int r = 0; r < 16; ++r) {
            int rowL = (r & 3) + 8 * (r >> 2) + 4 * half;
            sm[rowL][t * 32 + m] = f2bf(fmaxf(acc[t][r] + bb[t], 0.f));
        }
    }
    __syncthreads();
    int seg = lane & 7;
    int rbase = lane >> 3;
#pragma unroll
    for (int it = 0; it < 4; ++it) {
        int rowL = rbase + it * 8;
        int4 chunk = *(const int4*)&sm[rowL][seg * 8];
        *(int4*)(y + (size_t)(row0 + rowL) * HDIM + nh * 64 + seg * 8) = chunk;
    }
}

// ---------------- MFMA GEMM layer-3: split-N, relu -> per-graph pooled atomicAdd -----

__global__ __launch_bounds__(64) void k_gemm_pool(const ushort_t* __restrict__ Abuf,
                                                  const ushort_t* __restrict__ Wfrag,
                                                  const float* __restrict__ bias,
                                                  float* __restrict__ pooled) {
    int lane = threadIdx.x;
    int nh = blockIdx.x & 1;
    int row0 = (blockIdx.x >> 1) * 32;
    int m = lane & 31;
    int half = lane >> 5;

    f32x16 acc[2];
#pragma unroll
    for (int t = 0; t < 2; ++t) acc[t] = (f32x16)(0.f);

    float bb[2];
#pragma unroll
    for (int t = 0; t < 2; ++t) bb[t] = bias[nh * 64 + t * 32 + m];

    const ushort_t* arow = Abuf + (size_t)(row0 + m) * AK + half * 8;
    const ushort_t* wf = Wfrag + (size_t)lane * 8 + (size_t)nh * 2 * 16 * 512;

#pragma unroll
    for (int s = 0; s < 16; ++s) {
        bf16x8 afrag = *(const bf16x8*)(arow + s * 16);
#pragma unroll
        for (int t = 0; t < 2; ++t) {
            bf16x8 bfrag = *(const bf16x8*)(wf + (size_t)(t * 16 + s) * 512);
            acc[t] = __builtin_amdgcn_mfma_f32_32x32x16_bf16(afrag, bfrag, acc[t], 0, 0, 0);
        }
    }

    int g0 = row0 / SEG;
    int bnd = (g0 + 1) * SEG;
    int straddle = (row0 + 31 >= bnd);

#pragma unroll
    for (int t = 0; t < 2; ++t) {
        float s0 = 0.f, s1 = 0.f;
#pragma unroll
        for (int r = 0; r < 16; ++r) {
            int row = row0 + (r & 3) + 8 * (r >> 2) + 4 * half;
            float v = fmaxf(acc[t][r] + bb[t], 0.f);
            if (row < bnd) s0 += v; else s1 += v;
        }
        s0 += __shfl_xor(s0, 32);
        s1 += __shfl_xor(s1, 32);
        if (half == 0) {
            int coln = nh * 64 + t * 32 + m;
            atomicAdd(&pooled[g0 * HDIM + coln], s0);
            if (straddle) atomicAdd(&pooled[(g0 + 1) * HDIM + coln], s1);
        }
    }
}

// ---------------- mixup: bf16 y -> Abuf right half ----------------

__global__ void k_mixup_toA(const ushort_t* __restrict__ y, const int* __restrict__ perm,
                            const float* __restrict__ lam, ushort_t* __restrict__ Abuf) {
    int idx = blockIdx.x * 256 + threadIdx.x;
    int row = idx >> 5;
    int c4 = (idx & 31) * 4;
    float l = lam[0];
    float om = 1.f - l;
    int p = perm[row];
    ushort4 a = *(const ushort4*)(y + (size_t)row * HDIM + c4);
    ushort4 b = *(const ushort4*)(y + (size_t)p * HDIM + c4);
    ushort4 o;
    o.x = f2bf(l * bf2f(a.x) + om * bf2f(b.x));
    o.y = f2bf(l * bf2f(a.y) + om * bf2f(b.y));
    o.z = f2bf(l * bf2f(a.z) + om * bf2f(b.z));
    o.w = f2bf(l * bf2f(a.w) + om * bf2f(b.w));
    *(ushort4*)(Abuf + (size_t)row * AK + HDIM + c4) = o;
}

// ---------------- final: linear + log_softmax from pooled ----------------

__global__ __launch_bounds__(64) void k_final(const float* __restrict__ pooled,
                                              const float* __restrict__ Wlin,
                                              const float* __restrict__ blin,
                                              float* __restrict__ out) {
    int g = blockIdx.x;
    int lane = threadIdx.x;
    float2 v = *(const float2*)(pooled + (size_t)g * HDIM + lane * 2);
    float p[NOUT];
#pragma unroll
    for (int o = 0; o < NOUT; ++o)
        p[o] = v.x * Wlin[(size_t)(2 * lane) * NOUT + o] +
               v.y * Wlin[(size_t)(2 * lane + 1) * NOUT + o];
#pragma unroll
    for (int mask = 1; mask < 64; mask <<= 1)
#pragma unroll
        for (int o = 0; o < NOUT; ++o) p[o] += __shfl_xor(p[o], mask);
    if (lane == 0) {
        float lg[NOUT];
        float mx = -1e30f;
#pragma unroll
        for (int o = 0; o < NOUT; ++o) { lg[o] = p[o] + blin[o]; mx = fmaxf(mx, lg[o]); }
        float se = 0.f;
#pragma unroll
        for (int o = 0; o < NOUT; ++o) se += expf(lg[o] - mx);
        float lse = mx + logf(se);
#pragma unroll
        for (int o = 0; o < NOUT; ++o) out[g * NOUT + o] = lg[o] - lse;
    }
}

// ---------------- host ----------------

extern "C" void kernel_launch(void* const* d_in, const int* in_sizes, int n_in,
                              void* d_out, int out_size, void* d_ws, size_t ws_size,
                              hipStream_t stream) {
    const float* x0     = (const float*)d_in[0];
    const int*   edge   = (const int*)d_in[1];
    const int*   src    = edge;
    const int*   dst    = edge + N_EDGES;
    const float* lam    = (const float*)d_in[2];
    const int*   perm1  = (const int*)d_in[5];
    const int*   perm2  = (const int*)d_in[6];
    const float* W1_rel = (const float*)d_in[8];
    const float* b1_rel = (const float*)d_in[9];
    const float* W1_root= (const float*)d_in[10];
    const float* W2_rel = (const float*)d_in[11];
    const float* b2_rel = (const float*)d_in[12];
    const float* W2_root= (const float*)d_in[13];
    const float* W_lin  = (const float*)d_in[14];
    const float* b_lin  = (const float*)d_in[15];
    float* out = (float*)d_out;

    char* w = (char*)d_ws;
    size_t off = 0;
    auto alloc = [&](size_t bytes) -> void* {
        void* p = w + off;
        off = (off + bytes + 255) & ~(size_t)255;
        return p;
    };
    int* cnt8       = (int*)alloc((size_t)8 * N_NODES * 4);   // slice-major
    int* cnt        = (int*)alloc((size_t)N_NODES * 4);
    ushort_t* col_s = (ushort_t*)alloc((size_t)N_NODES * 8 * SSLOT * 2);
    ushort_t* col2  = (ushort_t*)alloc((size_t)N_NODES * SLOT * 2);
    ushort_t* Abuf   = (ushort_t*)alloc((size_t)N_NODES * AK * 2);
    ushort_t* ybuf   = (ushort_t*)alloc((size_t)N_NODES * HDIM * 2);
    ushort_t* Wfrag1 = (ushort_t*)alloc(32768 * 2);
    ushort_t* Wfrag2 = (ushort_t*)alloc(32768 * 2);
    float* pooled    = (float*)alloc((size_t)NGRAPH * HDIM * 4);

    hipMemsetAsync(cnt8, 0, (size_t)8 * N_NODES * 4, stream);

    // CSR build: XCD-sliced scatter + per-node compact
    k_scatter<<<N_EDGES / 256, 256, 0, stream>>>(src, dst, cnt8, col_s);
    // prep overlaps nothing but keeps the queue busy between dependent steps
    k_prep<<<6720, 256, 0, stream>>>(x0, Abuf, W1_rel, W1_root, W2_rel, W2_root,
                                     Wfrag1, Wfrag2, pooled);
    k_compact<<<N_NODES / 256, 256, 0, stream>>>(cnt8, col_s, col2, cnt);

    const int aggGrid  = N_NODES / 4;
    const int gemmGrid = (N_NODES / 32) * 2;
    const int elGrid   = (N_NODES * HDIM / 4) / 256;

    // layer 1
    k_aggregate<<<aggGrid, 256, 0, stream>>>(Abuf, cnt, col2);
    k_gemm_mfma<<<gemmGrid, 64, 0, stream>>>(Abuf, Wfrag1, b1_rel, ybuf);
    k_mixup_toA<<<elGrid, 256, 0, stream>>>(ybuf, perm1, lam, Abuf);
    // layer 2
    k_aggregate<<<aggGrid, 256, 0, stream>>>(Abuf, cnt, col2);
    k_gemm_mfma<<<gemmGrid, 64, 0, stream>>>(Abuf, Wfrag2, b2_rel, ybuf);
    k_mixup_toA<<<elGrid, 256, 0, stream>>>(ybuf, perm2, lam, Abuf);
    // layer 3 (mixup3 is a pooling no-op -> fused pool)
    k_aggregate<<<aggGrid, 256, 0, stream>>>(Abuf, cnt, col2);
    k_gemm_pool<<<gemmGrid, 64, 0, stream>>>(Abuf, Wfrag2, b2_rel, pooled);

    // classifier + log_softmax
    k_final<<<NGRAPH, 64, 0, stream>>>(pooled, W_lin, b_lin, out);
}

// Round 16
// 302.194 us; speedup vs baseline: 1.0843x; 1.0843x over previous
//
#include <hip/hip_runtime.h>

#define N_NODES 51200
#define N_EDGES 819200
#define HDIM 128
#define AK 256          // GEMM K = 2*HDIM (agg | x)
#define NGRAPH 128
#define SEG 400
#define NOUT 10
#define SLOT 64         // fixed col2 slot per node (deg ~ Poisson(16); P(>64) ~ 1e-13)

typedef unsigned short ushort_t;
typedef unsigned int uint_t;
typedef __attribute__((ext_vector_type(8))) short bf16x8;
typedef __attribute__((ext_vector_type(16))) float f32x16;

static __device__ __forceinline__ unsigned short f2bf(float f) {
    unsigned int u = __float_as_uint(f);
    unsigned int r = (u + 0x7fffu + ((u >> 16) & 1u)) >> 16;  // RNE
    return (unsigned short)r;
}
static __device__ __forceinline__ float bf2f(unsigned short h) {
    return __uint_as_float(((unsigned int)h) << 16);
}

// ---------------- edge scatter: entire CSR build, 4 edges/thread for atomic ILP -----
// R14 analysis: latency-bound on load->atomicAdd->store chain (VALUBusy 0.4%, HBM 10%);
// R15's XCD-slicing of writes was neutral-to-negative (write traffic is not the cost).
// 4 independent chains/thread; loads at stride 256 stay coalesced per wave.

__global__ void k_scatter(const int* __restrict__ src, const int* __restrict__ dst,
                          int* __restrict__ cnt, ushort_t* __restrict__ col2) {
    int base = blockIdx.x * 1024 + threadIdx.x;
    int d[4], p[4];
#pragma unroll
    for (int k = 0; k < 4; ++k) d[k] = dst[base + k * 256];
#pragma unroll
    for (int k = 0; k < 4; ++k) p[k] = atomicAdd(&cnt[d[k]], 1);
#pragma unroll
    for (int k = 0; k < 4; ++k)
        col2[(size_t)d[k] * SLOT + p[k]] = (ushort_t)src[base + k * 256];
}

// ---------------- prep: cast x0 -> Abuf right half, build Wfrags, zero pooled --------
// grid = 6400 (cast) + 128 (wfrag1) + 128 (wfrag2) + 64 (pooled zero) = 6720

__global__ void k_prep(const float* __restrict__ x, ushort_t* __restrict__ Abuf,
                       const float* __restrict__ W1rel, const float* __restrict__ W1root,
                       const float* __restrict__ W2rel, const float* __restrict__ W2root,
                       ushort_t* __restrict__ Wfrag1, ushort_t* __restrict__ Wfrag2,
                       float* __restrict__ pooled) {
    int b = blockIdx.x;
    if (b < 6400) {
        int idx = b * 256 + threadIdx.x;
        int row = idx >> 5;
        int c4 = (idx & 31) * 4;
        float4 v = *(const float4*)(x + (size_t)row * HDIM + c4);
        ushort4 h;
        h.x = f2bf(v.x); h.y = f2bf(v.y); h.z = f2bf(v.z); h.w = f2bf(v.w);
        *(ushort4*)(Abuf + (size_t)row * AK + HDIM + c4) = h;
    } else if (b < 6656) {
        int w2 = (b >= 6528);
        int tid = (b - (w2 ? 6528 : 6400)) * 256 + threadIdx.x;  // 0..32767
        const float* Wrel  = w2 ? W2rel : W1rel;
        const float* Wroot = w2 ? W2root : W1root;
        ushort_t* dstF     = w2 ? Wfrag2 : Wfrag1;
        int j = tid & 7;
        int l = (tid >> 3) & 63;
        int s = (tid >> 9) & 15;
        int t = tid >> 13;
        int k = 16 * s + (l >> 5) * 8 + j;
        int n = 32 * t + (l & 31);
        float v = (k < HDIM) ? Wrel[(size_t)k * HDIM + n]
                             : Wroot[(size_t)(k - HDIM) * HDIM + n];
        dstF[tid] = f2bf(v);
    } else {
        int i = (b - 6656) * 256 + threadIdx.x;  // 0..16383
        pooled[i] = 0.f;
    }
}

// ---------------- aggregation: quad-edge 16B gathers (R13) ----------------

__global__ __launch_bounds__(256) void k_aggregate(ushort_t* __restrict__ Abuf,
                                                   const int* __restrict__ cnt,
                                                   const ushort_t* __restrict__ col) {
    int wave = threadIdx.x >> 6;
    int lane = threadIdx.x & 63;
    int il = lane & 15;          // col group: cols 8*il..8*il+7 (16 B)
    int qe = lane >> 4;          // edge within quad: 0..3
    int node = blockIdx.x * 4 + wave;
    int beg = node * SLOT;
    int end = beg + cnt[node];

    const ushort_t* xsrc = Abuf + HDIM + (size_t)il * 8;

    float a[4][8];
#pragma unroll
    for (int j = 0; j < 4; ++j)
#pragma unroll
        for (int k = 0; k < 8; ++k) a[j][k] = 0.f;

    int e = beg;
    for (; e + 16 <= end; e += 16) {
        int c[4];
#pragma unroll
        for (int j = 0; j < 4; ++j) c[j] = (int)col[e + 4 * j + qe];
#pragma unroll
        for (int j = 0; j < 4; ++j) {
            uint4 v = *(const uint4*)(xsrc + (size_t)c[j] * AK);
            a[j][0] += __uint_as_float(v.x << 16);
            a[j][1] += __uint_as_float(v.x & 0xffff0000u);
            a[j][2] += __uint_as_float(v.y << 16);
            a[j][3] += __uint_as_float(v.y & 0xffff0000u);
            a[j][4] += __uint_as_float(v.z << 16);
            a[j][5] += __uint_as_float(v.z & 0xffff0000u);
            a[j][6] += __uint_as_float(v.w << 16);
            a[j][7] += __uint_as_float(v.w & 0xffff0000u);
        }
    }
    for (; e + 4 <= end; e += 4) {
        int c = (int)col[e + qe];
        uint4 v = *(const uint4*)(xsrc + (size_t)c * AK);
        a[0][0] += __uint_as_float(v.x << 16);
        a[0][1] += __uint_as_float(v.x & 0xffff0000u);
        a[0][2] += __uint_as_float(v.y << 16);
        a[0][3] += __uint_as_float(v.y & 0xffff0000u);
        a[0][4] += __uint_as_float(v.z << 16);
        a[0][5] += __uint_as_float(v.z & 0xffff0000u);
        a[0][6] += __uint_as_float(v.w << 16);
        a[0][7] += __uint_as_float(v.w & 0xffff0000u);
    }
    if (e < end) {
        int idx = e + qe;
        bool ok = idx < end;
        int c = (int)col[ok ? idx : e];
        uint4 v = *(const uint4*)(xsrc + (size_t)c * AK);
        a[1][0] += ok ? __uint_as_float(v.x << 16) : 0.f;
        a[1][1] += ok ? __uint_as_float(v.x & 0xffff0000u) : 0.f;
        a[1][2] += ok ? __uint_as_float(v.y << 16) : 0.f;
        a[1][3] += ok ? __uint_as_float(v.y & 0xffff0000u) : 0.f;
        a[1][4] += ok ? __uint_as_float(v.z << 16) : 0.f;
        a[1][5] += ok ? __uint_as_float(v.z & 0xffff0000u) : 0.f;
        a[1][6] += ok ? __uint_as_float(v.w << 16) : 0.f;
        a[1][7] += ok ? __uint_as_float(v.w & 0xffff0000u) : 0.f;
    }

    float s[8];
#pragma unroll
    for (int k = 0; k < 8; ++k) {
        s[k] = (a[0][k] + a[1][k]) + (a[2][k] + a[3][k]);
        s[k] += __shfl_xor(s[k], 16);
        s[k] += __shfl_xor(s[k], 32);
    }

    if (qe == 0) {
        uint4 o;
        o.x = (uint_t)f2bf(s[0]) | ((uint_t)f2bf(s[1]) << 16);
        o.y = (uint_t)f2bf(s[2]) | ((uint_t)f2bf(s[3]) << 16);
        o.z = (uint_t)f2bf(s[4]) | ((uint_t)f2bf(s[5]) << 16);
        o.w = (uint_t)f2bf(s[6]) | ((uint_t)f2bf(s[7]) << 16);
        *(uint4*)(Abuf + (size_t)node * AK + il * 8) = o;
    }
}

// ---------------- MFMA GEMM (layers 1-2): split-N, wave = 32 rows x 64 cols ---------

__global__ __launch_bounds__(64) void k_gemm_mfma(const ushort_t* __restrict__ Abuf,
                                                  const ushort_t* __restrict__ Wfrag,
                                                  const float* __restrict__ bias,
                                                  ushort_t* __restrict__ y) {
    __shared__ ushort_t sm[32][72];
    int lane = threadIdx.x;
    int nh = blockIdx.x & 1;
    int row0 = (blockIdx.x >> 1) * 32;
    int m = lane & 31;
    int half = lane >> 5;

    f32x16 acc[2];
#pragma unroll
    for (int t = 0; t < 2; ++t) acc[t] = (f32x16)(0.f);

    float bb[2];
#pragma unroll
    for (int t = 0; t < 2; ++t) bb[t] = bias[nh * 64 + t * 32 + m];

    const ushort_t* arow = Abuf + (size_t)(row0 + m) * AK + half * 8;
    const ushort_t* wf = Wfrag + (size_t)lane * 8 + (size_t)nh * 2 * 16 * 512;

#pragma unroll
    for (int s = 0; s < 16; ++s) {
        bf16x8 afrag = *(const bf16x8*)(arow + s * 16);
#pragma unroll
        for (int t = 0; t < 2; ++t) {
            bf16x8 bfrag = *(const bf16x8*)(wf + (size_t)(t * 16 + s) * 512);
            acc[t] = __builtin_amdgcn_mfma_f32_32x32x16_bf16(afrag, bfrag, acc[t], 0, 0, 0);
        }
    }

#pragma unroll
    for (int t = 0; t < 2; ++t) {
#pragma unroll
        for (int r = 0; r < 16; ++r) {
            int rowL = (r & 3) + 8 * (r >> 2) + 4 * half;
            sm[rowL][t * 32 + m] = f2bf(fmaxf(acc[t][r] + bb[t], 0.f));
        }
    }
    __syncthreads();
    int seg = lane & 7;
    int rbase = lane >> 3;
#pragma unroll
    for (int it = 0; it < 4; ++it) {
        int rowL = rbase + it * 8;
        int4 chunk = *(const int4*)&sm[rowL][seg * 8];
        *(int4*)(y + (size_t)(row0 + rowL) * HDIM + nh * 64 + seg * 8) = chunk;
    }
}

// ---------------- MFMA GEMM layer-3: split-N, relu -> per-graph pooled atomicAdd -----

__global__ __launch_bounds__(64) void k_gemm_pool(const ushort_t* __restrict__ Abuf,
                                                  const ushort_t* __restrict__ Wfrag,
                                                  const float* __restrict__ bias,
                                                  float* __restrict__ pooled) {
    int lane = threadIdx.x;
    int nh = blockIdx.x & 1;
    int row0 = (blockIdx.x >> 1) * 32;
    int m = lane & 31;
    int half = lane >> 5;

    f32x16 acc[2];
#pragma unroll
    for (int t = 0; t < 2; ++t) acc[t] = (f32x16)(0.f);

    float bb[2];
#pragma unroll
    for (int t = 0; t < 2; ++t) bb[t] = bias[nh * 64 + t * 32 + m];

    const ushort_t* arow = Abuf + (size_t)(row0 + m) * AK + half * 8;
    const ushort_t* wf = Wfrag + (size_t)lane * 8 + (size_t)nh * 2 * 16 * 512;

#pragma unroll
    for (int s = 0; s < 16; ++s) {
        bf16x8 afrag = *(const bf16x8*)(arow + s * 16);
#pragma unroll
        for (int t = 0; t < 2; ++t) {
            bf16x8 bfrag = *(const bf16x8*)(wf + (size_t)(t * 16 + s) * 512);
            acc[t] = __builtin_amdgcn_mfma_f32_32x32x16_bf16(afrag, bfrag, acc[t], 0, 0, 0);
        }
    }

    int g0 = row0 / SEG;
    int bnd = (g0 + 1) * SEG;
    int straddle = (row0 + 31 >= bnd);

#pragma unroll
    for (int t = 0; t < 2; ++t) {
        float s0 = 0.f, s1 = 0.f;
#pragma unroll
        for (int r = 0; r < 16; ++r) {
            int row = row0 + (r & 3) + 8 * (r >> 2) + 4 * half;
            float v = fmaxf(acc[t][r] + bb[t], 0.f);
            if (row < bnd) s0 += v; else s1 += v;
        }
        s0 += __shfl_xor(s0, 32);
        s1 += __shfl_xor(s1, 32);
        if (half == 0) {
            int coln = nh * 64 + t * 32 + m;
            atomicAdd(&pooled[g0 * HDIM + coln], s0);
            if (straddle) atomicAdd(&pooled[(g0 + 1) * HDIM + coln], s1);
        }
    }
}

// ---------------- mixup: bf16 y -> Abuf right half ----------------

__global__ void k_mixup_toA(const ushort_t* __restrict__ y, const int* __restrict__ perm,
                            const float* __restrict__ lam, ushort_t* __restrict__ Abuf) {
    int idx = blockIdx.x * 256 + threadIdx.x;
    int row = idx >> 5;
    int c4 = (idx & 31) * 4;
    float l = lam[0];
    float om = 1.f - l;
    int p = perm[row];
    ushort4 a = *(const ushort4*)(y + (size_t)row * HDIM + c4);
    ushort4 b = *(const ushort4*)(y + (size_t)p * HDIM + c4);
    ushort4 o;
    o.x = f2bf(l * bf2f(a.x) + om * bf2f(b.x));
    o.y = f2bf(l * bf2f(a.y) + om * bf2f(b.y));
    o.z = f2bf(l * bf2f(a.z) + om * bf2f(b.z));
    o.w = f2bf(l * bf2f(a.w) + om * bf2f(b.w));
    *(ushort4*)(Abuf + (size_t)row * AK + HDIM + c4) = o;
}

// ---------------- final: linear + log_softmax from pooled ----------------

__global__ __launch_bounds__(64) void k_final(const float* __restrict__ pooled,
                                              const float* __restrict__ Wlin,
                                              const float* __restrict__ blin,
                                              float* __restrict__ out) {
    int g = blockIdx.x;
    int lane = threadIdx.x;
    float2 v = *(const float2*)(pooled + (size_t)g * HDIM + lane * 2);
    float p[NOUT];
#pragma unroll
    for (int o = 0; o < NOUT; ++o)
        p[o] = v.x * Wlin[(size_t)(2 * lane) * NOUT + o] +
               v.y * Wlin[(size_t)(2 * lane + 1) * NOUT + o];
#pragma unroll
    for (int mask = 1; mask < 64; mask <<= 1)
#pragma unroll
        for (int o = 0; o < NOUT; ++o) p[o] += __shfl_xor(p[o], mask);
    if (lane == 0) {
        float lg[NOUT];
        float mx = -1e30f;
#pragma unroll
        for (int o = 0; o < NOUT; ++o) { lg[o] = p[o] + blin[o]; mx = fmaxf(mx, lg[o]); }
        float se = 0.f;
#pragma unroll
        for (int o = 0; o < NOUT; ++o) se += expf(lg[o] - mx);
        float lse = mx + logf(se);
#pragma unroll
        for (int o = 0; o < NOUT; ++o) out[g * NOUT + o] = lg[o] - lse;
    }
}

// ---------------- host ----------------

extern "C" void kernel_launch(void* const* d_in, const int* in_sizes, int n_in,
                              void* d_out, int out_size, void* d_ws, size_t ws_size,
                              hipStream_t stream) {
    const float* x0     = (const float*)d_in[0];
    const int*   edge   = (const int*)d_in[1];
    const int*   src    = edge;
    const int*   dst    = edge + N_EDGES;
    const float* lam    = (const float*)d_in[2];
    const int*   perm1  = (const int*)d_in[5];
    const int*   perm2  = (const int*)d_in[6];
    const float* W1_rel = (const float*)d_in[8];
    const float* b1_rel = (const float*)d_in[9];
    const float* W1_root= (const float*)d_in[10];
    const float* W2_rel = (const float*)d_in[11];
    const float* b2_rel = (const float*)d_in[12];
    const float* W2_root= (const float*)d_in[13];
    const float* W_lin  = (const float*)d_in[14];
    const float* b_lin  = (const float*)d_in[15];
    float* out = (float*)d_out;

    char* w = (char*)d_ws;
    size_t off = 0;
    auto alloc = [&](size_t bytes) -> void* {
        void* p = w + off;
        off = (off + bytes + 255) & ~(size_t)255;
        return p;
    };
    int* cnt       = (int*)alloc((size_t)N_NODES * 4);
    ushort_t* col2 = (ushort_t*)alloc((size_t)N_NODES * SLOT * 2);
    ushort_t* Abuf   = (ushort_t*)alloc((size_t)N_NODES * AK * 2);
    ushort_t* ybuf   = (ushort_t*)alloc((size_t)N_NODES * HDIM * 2);
    ushort_t* Wfrag1 = (ushort_t*)alloc(32768 * 2);
    ushort_t* Wfrag2 = (ushort_t*)alloc(32768 * 2);
    float* pooled    = (float*)alloc((size_t)NGRAPH * HDIM * 4);

    hipMemsetAsync(cnt, 0, (size_t)N_NODES * 4, stream);

    // CSR build: ONE scatter kernel, 4 edges/thread (atomic ILP)
    k_scatter<<<N_EDGES / 1024, 256, 0, stream>>>(src, dst, cnt, col2);

    // prep: cast + wfrags + pooled zero
    k_prep<<<6720, 256, 0, stream>>>(x0, Abuf, W1_rel, W1_root, W2_rel, W2_root,
                                     Wfrag1, Wfrag2, pooled);

    const int aggGrid  = N_NODES / 4;
    const int gemmGrid = (N_NODES / 32) * 2;
    const int elGrid   = (N_NODES * HDIM / 4) / 256;

    // layer 1
    k_aggregate<<<aggGrid, 256, 0, stream>>>(Abuf, cnt, col2);
    k_gemm_mfma<<<gemmGrid, 64, 0, stream>>>(Abuf, Wfrag1, b1_rel, ybuf);
    k_mixup_toA<<<elGrid, 256, 0, stream>>>(ybuf, perm1, lam, Abuf);
    // layer 2
    k_aggregate<<<aggGrid, 256, 0, stream>>>(Abuf, cnt, col2);
    k_gemm_mfma<<<gemmGrid, 64, 0, stream>>>(Abuf, Wfrag2, b2_rel, ybuf);
    k_mixup_toA<<<elGrid, 256, 0, stream>>>(ybuf, perm2, lam, Abuf);
    // layer 3 (mixup3 is a pooling no-op -> fused pool)
    k_aggregate<<<aggGrid, 256, 0, stream>>>(Abuf, cnt, col2);
    k_gemm_pool<<<gemmGrid, 64, 0, stream>>>(Abuf, Wfrag2, b2_rel, pooled);

    // classifier + log_softmax
    k_final<<<NGRAPH, 64, 0, stream>>>(pooled, W_lin, b_lin, out);
}